// Round 4
// baseline (192.808 us; speedup 1.0000x reference)
//
#include <hip/hip_runtime.h>
#include <hip/hip_bf16.h>
#include <stdint.h>

#define TT 2048
#define DD 1024
#define HH 16
#define HDIM 64
#define BB 4
#define MROWS 8192   // B*T
#define LOG2E 1.44269504088896340736f

typedef __attribute__((ext_vector_type(8))) short short8;
typedef __attribute__((ext_vector_type(4))) float floatx4;

__device__ __forceinline__ ushort f2bf(float f){
  uint32_t u = __builtin_bit_cast(uint32_t, f);
  u = u + 0x7fffu + ((u >> 16) & 1u);   // RNE
  return (ushort)(u >> 16);
}

__device__ __forceinline__ uint32_t cvtpk(float lo, float hi){
  uint32_t r;
  asm("v_cvt_pk_bf16_f32 %0, %1, %2" : "=v"(r) : "v"(lo), "v"(hi));
  return r;
}

__device__ __forceinline__ float exp2a(float x){
  float r;
  asm("v_exp_f32 %0, %1" : "=v"(r) : "v"(x));
  return r;
}

__device__ __forceinline__ void gld16(const void* g, void* l){
  __builtin_amdgcn_global_load_lds((const __attribute__((address_space(1))) uint32_t*)g,
                                   (__attribute__((address_space(3))) uint32_t*)l, 16, 0, 0);
}

// ---------------- fp32 -> bf16 conversion ----------------
__global__ void cvt_bf16(const float* __restrict__ src, ushort* __restrict__ dst, int n4){
  int i = blockIdx.x*blockDim.x + threadIdx.x;
  if (i < n4){
    float4 v = ((const float4*)src)[i];
    ushort4 o;
    o.x = f2bf(v.x); o.y = f2bf(v.y); o.z = f2bf(v.z); o.w = f2bf(v.w);
    ((ushort4*)dst)[i] = o;
  }
}

// ---------------- QKV projection GEMM: C = A @ W^T + b ----------------
// Q scaled by 0.125*log2e (attn runs softmax in exp2 domain).
// Q,K written [B,H,T,HD]; V written TRANSPOSED [B,H,HD,T].
__global__ __launch_bounds__(256) void qkv_gemm(
    const ushort* __restrict__ A, const ushort* __restrict__ Wall,
    const float* __restrict__ bq, const float* __restrict__ bk, const float* __restrict__ bv,
    ushort* __restrict__ Qo, ushort* __restrict__ Ko, ushort* __restrict__ Vo)
{
  __shared__ __align__(16) ushort sA[128*64];
  __shared__ __align__(16) ushort sB[128*64];
  const int mat = blockIdx.z;
  const ushort* W = Wall + (size_t)mat*DD*DD;
  const float* bias = (mat==0)? bq : (mat==1? bk : bv);
  ushort* out = (mat==0)? Qo : (mat==1? Ko : Vo);
  const float oscale = (mat==0)? 0.125f*LOG2E : 1.0f;
  const int m0 = blockIdx.x*128, n0 = blockIdx.y*128;
  const int tid = threadIdx.x, lane = tid & 63, wid = tid >> 6;
  const int wm = (wid>>1)*64, wn = (wid&1)*64;
  const int c = lane & 15, g = lane >> 4;
  const int srow = lane >> 3;
  const int scol = (lane & 7) * 8;

  floatx4 acc[4][4];
  #pragma unroll
  for (int i=0;i<4;i++)
    #pragma unroll
    for(int j=0;j<4;j++) acc[i][j] = (floatx4){0.f,0.f,0.f,0.f};

  for (int k0 = 0; k0 < DD; k0 += 64){
    #pragma unroll
    for (int j=0;j<4;j++){
      int chunk = wid*4 + j;
      int row = chunk*8 + srow;
      gld16(A + (size_t)(m0+row)*DD + k0 + scol, sA + chunk*512);
      gld16(W + (size_t)(n0+row)*DD + k0 + scol, sB + chunk*512);
    }
    __syncthreads();
    #pragma unroll
    for (int ch=0; ch<2; ++ch){
      short8 af[4], bfr[4];
      #pragma unroll
      for (int mf=0; mf<4; ++mf)
        af[mf] = *(const short8*)(sA + (wm + mf*16 + c)*64 + ch*32 + g*8);
      #pragma unroll
      for (int nf=0; nf<4; ++nf)
        bfr[nf] = *(const short8*)(sB + (wn + nf*16 + c)*64 + ch*32 + g*8);
      #pragma unroll
      for (int mf=0; mf<4; ++mf)
        #pragma unroll
        for (int nf=0; nf<4; ++nf)
          acc[mf][nf] = __builtin_amdgcn_mfma_f32_16x16x32_bf16(af[mf], bfr[nf], acc[mf][nf], 0,0,0);
    }
    __syncthreads();
  }
  #pragma unroll
  for (int nf=0; nf<4; ++nf){
    int col = n0 + wn + nf*16 + c;
    float bval = bias[col];
    int h = col >> 6, hd = col & 63;
    #pragma unroll
    for (int mf=0; mf<4; ++mf){
      int rowb = m0 + wm + mf*16 + g*4;
      int b = rowb >> 11, t = rowb & (TT-1);
      if (mat == 2){
        // transposed store: VT[b,h,hd,t..t+3], 4 consecutive t = 8B
        ushort4 st;
        st.x = f2bf(acc[mf][nf][0] + bval);
        st.y = f2bf(acc[mf][nf][1] + bval);
        st.z = f2bf(acc[mf][nf][2] + bval);
        st.w = f2bf(acc[mf][nf][3] + bval);
        *(ushort4*)(out + ((size_t)(b*HH + h)*HDIM + hd)*TT + t) = st;
      } else {
        #pragma unroll
        for (int r=0; r<4; ++r){
          float v = (acc[mf][nf][r] + bval) * oscale;
          out[((size_t)(b*HH + h)*TT + (t + r))*HDIM + hd] = f2bf(v);
        }
      }
    }
  }
}

// ---------------- causal flash attention (LDS fragment-major, pipelined) ------
// grid (8, B*H), 4 waves. Block x handles q-tiles {x, 15-x} of 128 rows each.
// K/V tiles staged in LDS in FRAGMENT-MAJOR layout: LDS block (ch*4+nt) holds the
// exact 64-lane MFMA fragment at lane*16B (global source is pre-permuted; LDS dest
// is linear as global_load_lds requires). ds_reads are lane-linear: zero conflicts.
__global__ __launch_bounds__(256,2) void attn_fwd(
    const ushort* __restrict__ Q, const ushort* __restrict__ K, const ushort* __restrict__ VT,
    const float* __restrict__ amask, float* __restrict__ O)
{
  __shared__ __align__(16) ushort sKt[2][4096];
  __shared__ __align__(16) ushort sVt[2][4096];
  __shared__ __align__(16) float  sAm[TT];
  __shared__ __align__(16) uint32_t sP[4][16*36];

  const int bh = blockIdx.y, b = bh >> 4, h = bh & 15;
  const int tid = threadIdx.x, lane = tid & 63, w = tid >> 6;
  const int c = lane & 15, g = lane >> 4;
  uint32_t* sPw = sP[w];

  const int qt1 = blockIdx.x, qt2 = 15 - qt1;
  const int nt1 = 2*qt1 + 2;
  const int ntot = 34;

  const char* Kbh = (const char*)(K  + (size_t)bh*TT*HDIM);
  const char* Vbh = (const char*)(VT + (size_t)bh*HDIM*TT);

  // fragment-major staging: wave w stages K blocks {w, w+4} and V blocks {w, w+4}.
  // K block (ch*4+nt), lane l <- K[kv0 + nt*16 + (l&15)][ch*32 + (l>>4)*8 ..+8]
  // V block (ch*4+d),  lane l <- VT[d*16 + (l&15)][kv0 + ch*32 + (l>>4)*8 ..+8]
  auto stage = [&](int f){
    int it = (f >= nt1) ? f - nt1 : f;
    int kv0 = it*64;
    int buf = f & 1;
    const char* ksrc = Kbh + (size_t)(kv0 + w*16 + c)*128 + (lane>>4)*16;
    gld16(ksrc,      &sKt[buf][(size_t)w*512]);
    gld16(ksrc + 64, &sKt[buf][(size_t)(4+w)*512]);
    const char* vsrc = Vbh + (size_t)(w*16 + c)*(TT*2) + (size_t)kv0*2 + (lane>>4)*16;
    gld16(vsrc,      &sVt[buf][(size_t)w*512]);
    gld16(vsrc + 64, &sVt[buf][(size_t)(4+w)*512]);
  };

  short8 qf[2][2];
  auto loadq = [&](int qt_){
    #pragma unroll
    for (int grp=0; grp<2; ++grp){
      int qmy = qt_*128 + grp*64 + w*16 + c;
      #pragma unroll
      for (int ch=0; ch<2; ++ch)
        qf[grp][ch] = *(const short8*)(Q + ((size_t)bh*TT + qmy)*HDIM + ch*32 + g*8);
    }
  };

  floatx4 oacc[2][4];
  float mreg[2], lreg[2];
  auto reset_state = [&](){
    #pragma unroll
    for (int grp=0; grp<2; ++grp){
      mreg[grp] = -1e30f; lreg[grp] = 0.f;
      #pragma unroll
      for (int d=0; d<4; ++d) oacc[grp][d] = (floatx4){0.f,0.f,0.f,0.f};
    }
  };
  auto writeout = [&](int qt_){
    #pragma unroll
    for (int grp=0; grp<2; ++grp){
      int qmy = qt_*128 + grp*64 + w*16 + c;
      float rl = 1.f / lreg[grp];
      #pragma unroll
      for (int d=0; d<4; ++d){
        float4 st;
        st.x = oacc[grp][d][0]*rl; st.y = oacc[grp][d][1]*rl;
        st.z = oacc[grp][d][2]*rl; st.w = oacc[grp][d][3]*rl;
        *(float4*)(O + ((size_t)b*TT + qmy)*DD + h*HDIM + d*16 + g*4) = st;
      }
    }
  };

  // prologue: amask -> LDS (exp2 domain), Q frags, stage tile 0
  {
    const float* amb = amask + (size_t)b*TT;
    int i0 = tid*8;
    float4 a0 = *(const float4*)(amb + i0);
    float4 a1 = *(const float4*)(amb + i0 + 4);
    a0.x*=LOG2E; a0.y*=LOG2E; a0.z*=LOG2E; a0.w*=LOG2E;
    a1.x*=LOG2E; a1.y*=LOG2E; a1.z*=LOG2E; a1.w*=LOG2E;
    *(float4*)(sAm + i0) = a0;
    *(float4*)(sAm + i0 + 4) = a1;
  }
  loadq(qt1);
  reset_state();
  stage(0);
  __syncthreads();

  int qt = qt1, base = qt1*128;

  for (int f=0; f<ntot; ++f){
    const int it = (f >= nt1) ? f - nt1 : f;
    if (f == nt1){
      writeout(qt1);
      reset_state();
      loadq(qt2);
      qt = qt2; base = qt2*128;
    }
    if (f+1 < ntot){
      stage(f+1);
      asm volatile("s_waitcnt vmcnt(4)" ::: "memory");
    } else {
      asm volatile("s_waitcnt vmcnt(0)" ::: "memory");
    }
    __builtin_amdgcn_s_barrier();
    __builtin_amdgcn_sched_barrier(0);

    const int kv0 = it*64, buf = f & 1;
    const ushort* bK = sKt[buf];
    const ushort* bV = sVt[buf];

    // lane-linear fragment reads (conflict-free)
    short8 kf[2][4];
    #pragma unroll
    for (int ch=0; ch<2; ++ch)
      #pragma unroll
      for (int nt=0; nt<4; ++nt)
        kf[ch][nt] = *(const short8*)(bK + (ch*4+nt)*512 + lane*8);
    float4 amv[4];
    #pragma unroll
    for (int nt=0; nt<4; ++nt)
      amv[nt] = *(const float4*)(sAm + kv0 + nt*16 + g*4);

    const bool act0 = (it <= 2*qt);
    short8 pbr[2][2];
    #pragma unroll
    for (int grp=0; grp<2; ++grp){
      if (grp==0 && !act0) continue;
      const int qrow0 = base + grp*64 + w*16;
      const int qmy = qrow0 + c;
      const bool caus = (kv0 + 63 > qrow0);
      floatx4 sacc[4];
      #pragma unroll
      for (int i=0;i<4;i++) sacc[i] = (floatx4){0.f,0.f,0.f,0.f};
      __builtin_amdgcn_s_setprio(1);
      #pragma unroll
      for (int ch=0; ch<2; ++ch)
        #pragma unroll
        for (int nt=0; nt<4; ++nt)
          sacc[nt] = __builtin_amdgcn_mfma_f32_16x16x32_bf16(kf[ch][nt], qf[grp][ch], sacc[nt], 0,0,0);
      __builtin_amdgcn_s_setprio(0);

      float p[4][4];
      float mx = -1e30f;
      #pragma unroll
      for (int nt=0; nt<4; ++nt)
        #pragma unroll
        for (int r=0; r<4; ++r){
          float s = sacc[nt][r] + ((const float*)&amv[nt])[r];
          if (caus){
            int kv = kv0 + nt*16 + g*4 + r;
            s = (kv > qmy) ? -1e30f : s;
          }
          p[nt][r] = s;
          mx = fmaxf(mx, s);
        }
      mx = fmaxf(mx, __shfl_xor(mx, 16));
      mx = fmaxf(mx, __shfl_xor(mx, 32));
      if (!__all(mx <= mreg[grp] + 8.f)){
        float mn = fmaxf(mreg[grp], mx);
        float sc = exp2a(mreg[grp] - mn);
        mreg[grp] = mn;
        lreg[grp] *= sc;
        #pragma unroll
        for (int d=0; d<4; ++d)
          #pragma unroll
          for (int r=0; r<4; ++r) oacc[grp][d][r] *= sc;
      }
      float ps = 0.f;
      #pragma unroll
      for (int nt=0; nt<4; ++nt)
        #pragma unroll
        for (int r=0; r<4; ++r){
          float e = exp2a(p[nt][r] - mreg[grp]);
          p[nt][r] = e;
          ps += e;
        }
      ps += __shfl_xor(ps, 16);
      ps += __shfl_xor(ps, 32);
      lreg[grp] += ps;
      // pack P -> bf16, bounce through wave-private LDS
      #pragma unroll
      for (int nt=0; nt<4; ++nt){
        uint2 pk;
        pk.x = cvtpk(p[nt][0], p[nt][1]);
        pk.y = cvtpk(p[nt][2], p[nt][3]);
        *(uint2*)(sPw + 36*c + 8*nt + 2*g) = pk;
      }
      pbr[grp][0] = *(const short8*)(sPw + 36*c + 4*g);
      pbr[grp][1] = *(const short8*)(sPw + 36*c + 16 + 4*g);
    }

    short8 vf[2][4];
    #pragma unroll
    for (int ch=0; ch<2; ++ch)
      #pragma unroll
      for (int d=0; d<4; ++d)
        vf[ch][d] = *(const short8*)(bV + (ch*4+d)*512 + lane*8);
    __builtin_amdgcn_s_setprio(1);
    #pragma unroll
    for (int grp=0; grp<2; ++grp){
      if (grp==0 && !act0) continue;
      #pragma unroll
      for (int d=0; d<4; ++d)
        #pragma unroll
        for (int ch=0; ch<2; ++ch)
          oacc[grp][d] = __builtin_amdgcn_mfma_f32_16x16x32_bf16(vf[ch][d], pbr[grp][ch], oacc[grp][d], 0,0,0);
    }
    __builtin_amdgcn_s_setprio(0);

    __builtin_amdgcn_sched_barrier(0);
    __builtin_amdgcn_s_barrier();
  }
  writeout(qt2);
}

extern "C" void kernel_launch(void* const* d_in, const int* in_sizes, int n_in,
                              void* d_out, int out_size, void* d_ws, size_t ws_size,
                              hipStream_t stream){
  const float* hs    = (const float*)d_in[0];
  const float* amask = (const float*)d_in[1];
  const float* Wq    = (const float*)d_in[2];
  const float* bq    = (const float*)d_in[3];
  const float* Wk    = (const float*)d_in[4];
  const float* bk    = (const float*)d_in[5];
  const float* Wv    = (const float*)d_in[6];
  const float* bv    = (const float*)d_in[7];
  float* out = (float*)d_out;

  ushort* hsb = (ushort*)d_ws;                    // [8192][1024] bf16
  ushort* wb  = hsb + (size_t)MROWS*DD;           // 3x [1024][1024] bf16
  ushort* qb  = wb  + (size_t)3*DD*DD;            // [B,H,T,HD]
  ushort* kb  = qb  + (size_t)MROWS*DD;           // [B,H,T,HD]
  ushort* vtb = kb  + (size_t)MROWS*DD;           // [B,H,HD,T] (written directly by qkv_gemm)

  cvt_bf16<<<(MROWS*DD/4)/256, 256, 0, stream>>>(hs, hsb, MROWS*DD/4);
  cvt_bf16<<<(DD*DD/4)/256, 256, 0, stream>>>(Wq, wb,            DD*DD/4);
  cvt_bf16<<<(DD*DD/4)/256, 256, 0, stream>>>(Wk, wb + DD*DD,    DD*DD/4);
  cvt_bf16<<<(DD*DD/4)/256, 256, 0, stream>>>(Wv, wb + 2*DD*DD,  DD*DD/4);

  qkv_gemm<<<dim3(MROWS/128, DD/128, 3), 256, 0, stream>>>(hsb, wb, bq, bk, bv, qb, kb, vtb);
  attn_fwd<<<dim3(8, BB*HH), 256, 0, stream>>>(qb, kb, vtb, amask, out);
}